// Round 1
// baseline (1549.801 us; speedup 1.0000x reference)
//
#include <hip/hip_runtime.h>
#include <math.h>

namespace {

constexpr int BT  = 8 * 4096;   // 32768 tokens
constexpr int DIM = 1024;       // model dim
constexpr int NE  = 64;         // experts
constexpr int NS  = 8;          // slots per expert
constexpr int NP  = NE * NS;    // 512 total slots
constexpr int HID = 256;

// ---------------------------------------------------------------------------
// GEMM1: mat[BT][NP] = flat[BT][DIM] @ em[DIM][NP]   (fp32, 64x64 tile, BK=16)
// ---------------------------------------------------------------------------
__global__ __launch_bounds__(256) void k_gemm1(const float* __restrict__ A,
                                               const float* __restrict__ B,
                                               float* __restrict__ C) {
  __shared__ float As[16 * 64];   // [k][m]
  __shared__ float Bs[16 * 64];   // [k][n]
  const int tid = threadIdx.x;
  const int m0 = blockIdx.x * 64;
  const int n0 = blockIdx.y * 64;
  const int tx = tid & 15, ty = tid >> 4;
  const int am = tid >> 2, ak = (tid & 3) * 4;   // A load: row am, 4 k's
  const int bk = tid >> 4, bn = (tid & 15) * 4;  // B load: row bk, 4 n's
  float acc[4][4] = {};
  for (int kk = 0; kk < DIM; kk += 16) {
    float4 av = *(const float4*)(A + (size_t)(m0 + am) * DIM + kk + ak);
    float4 bv = *(const float4*)(B + (size_t)(kk + bk) * NP + n0 + bn);
    __syncthreads();
    As[(ak + 0) * 64 + am] = av.x;
    As[(ak + 1) * 64 + am] = av.y;
    As[(ak + 2) * 64 + am] = av.z;
    As[(ak + 3) * 64 + am] = av.w;
    *(float4*)(Bs + bk * 64 + bn) = bv;
    __syncthreads();
#pragma unroll
    for (int k = 0; k < 16; ++k) {
      float4 a4 = *(const float4*)(As + k * 64 + ty * 4);
      float4 b4 = *(const float4*)(Bs + k * 64 + tx * 4);
      float a[4] = {a4.x, a4.y, a4.z, a4.w};
      float b[4] = {b4.x, b4.y, b4.z, b4.w};
#pragma unroll
      for (int i = 0; i < 4; ++i)
#pragma unroll
        for (int j = 0; j < 4; ++j) acc[i][j] += a[i] * b[j];
    }
  }
#pragma unroll
  for (int i = 0; i < 4; ++i) {
    float4 o = make_float4(acc[i][0], acc[i][1], acc[i][2], acc[i][3]);
    *(float4*)(C + (size_t)(m0 + ty * 4 + i) * NP + n0 + tx * 4) = o;
  }
}

// ---------------------------------------------------------------------------
// Column softmax stats (over tokens, per slot): two-stage online max/sumexp.
// Stage A: grid (NP/64 colgroups, 64 row-chunks of 512), block 256 = 64x4.
// ---------------------------------------------------------------------------
__global__ __launch_bounds__(256) void k_colpart(const float* __restrict__ mat,
                                                 float* __restrict__ pm,
                                                 float* __restrict__ pz) {
  const int col = blockIdx.x * 64 + (threadIdx.x & 63);
  const int tyy = threadIdx.x >> 6;
  const int r0 = blockIdx.y * 512;
  float m = -INFINITY, z = 0.f;
  for (int r = r0 + tyy; r < r0 + 512; r += 4) {
    float v = mat[(size_t)r * NP + col];
    if (v <= m) {
      z += __expf(v - m);
    } else {
      z = z * __expf(m - v) + 1.f;
      m = v;
    }
  }
  __shared__ float smx[256], szx[256];
  smx[threadIdx.x] = m;
  szx[threadIdx.x] = z;
  __syncthreads();
  if (tyy == 0) {
    for (int q = 1; q < 4; ++q) {
      float m2 = smx[threadIdx.x + q * 64], z2 = szx[threadIdx.x + q * 64];
      float mm = fmaxf(m, m2);
      z = z * __expf(m - mm) + z2 * __expf(m2 - mm);
      m = mm;
    }
    pm[(size_t)blockIdx.y * NP + col] = m;
    pz[(size_t)blockIdx.y * NP + col] = z;
  }
}

__global__ void k_colfinal(const float* __restrict__ pm, const float* __restrict__ pz,
                           float* __restrict__ colM, float* __restrict__ colIZ) {
  const int c = threadIdx.x;  // <<<1, NP>>>
  float m = -INFINITY, z = 0.f;
  for (int q = 0; q < 64; ++q) {
    float m2 = pm[(size_t)q * NP + c], z2 = pz[(size_t)q * NP + c];
    float mm = fmaxf(m, m2);
    z = z * __expf(m - mm) + z2 * __expf(m2 - mm);
    m = mm;
  }
  colM[c] = m;
  colIZ[c] = 1.f / z;
}

// ---------------------------------------------------------------------------
// Row softmax stats (over 512 slots per token): one wave per token.
// ---------------------------------------------------------------------------
__global__ __launch_bounds__(256) void k_rowstats(const float* __restrict__ mat,
                                                  float* __restrict__ rowM,
                                                  float* __restrict__ rowIZ) {
  const int w = threadIdx.x >> 6;
  const int lane = threadIdx.x & 63;
  const int t = blockIdx.x * 4 + w;
  const float4* row = (const float4*)(mat + (size_t)t * NP);
  float4 v1 = row[lane];
  float4 v2 = row[lane + 64];
  float m = fmaxf(fmaxf(fmaxf(v1.x, v1.y), fmaxf(v1.z, v1.w)),
                  fmaxf(fmaxf(v2.x, v2.y), fmaxf(v2.z, v2.w)));
#pragma unroll
  for (int o = 32; o; o >>= 1) m = fmaxf(m, __shfl_xor(m, o));
  float s = __expf(v1.x - m) + __expf(v1.y - m) + __expf(v1.z - m) + __expf(v1.w - m) +
            __expf(v2.x - m) + __expf(v2.y - m) + __expf(v2.z - m) + __expf(v2.w - m);
#pragma unroll
  for (int o = 32; o; o >>= 1) s += __shfl_xor(s, o);
  if (lane == 0) {
    rowM[t] = m;
    rowIZ[t] = 1.f / s;
  }
}

// ---------------------------------------------------------------------------
// GEMM2 (dispatch): xhat[NP][DIM] += P^T @ flat, P[t][s] = exp(mat-m_s)*invZ_s
// applied on the fly during A staging. Split-K (32 chunks) + fp32 atomics.
// mat is [t][s] which is exactly A in [k][m] layout -> coalesced staging.
// ---------------------------------------------------------------------------
__global__ __launch_bounds__(256) void k_gemm2(const float* __restrict__ mat,
                                               const float* __restrict__ flat,
                                               const float* __restrict__ colM,
                                               const float* __restrict__ colIZ,
                                               float* __restrict__ xhat) {
  __shared__ float As[16 * 64];
  __shared__ float Bs[16 * 64];
  __shared__ float sm[64], sz[64];
  const int tid = threadIdx.x;
  const int s0 = blockIdx.x * 64;
  const int d0 = blockIdx.y * 64;
  const int t0 = blockIdx.z * (BT / 32);
  if (tid < 64) {
    sm[tid] = colM[s0 + tid];
    sz[tid] = colIZ[s0 + tid];
  }
  const int tx = tid & 15, ty = tid >> 4;
  const int lk = tid >> 4;        // t-row within BK
  const int lm = (tid & 15) * 4;  // s/d offset
  float acc[4][4] = {};
  for (int kk = 0; kk < BT / 32; kk += 16) {
    const int t = t0 + kk + lk;
    float4 av = *(const float4*)(mat + (size_t)t * NP + s0 + lm);
    float4 bv = *(const float4*)(flat + (size_t)t * DIM + d0 + lm);
    __syncthreads();
    float4 pa;
    pa.x = __expf(av.x - sm[lm + 0]) * sz[lm + 0];
    pa.y = __expf(av.y - sm[lm + 1]) * sz[lm + 1];
    pa.z = __expf(av.z - sm[lm + 2]) * sz[lm + 2];
    pa.w = __expf(av.w - sm[lm + 3]) * sz[lm + 3];
    *(float4*)(As + lk * 64 + lm) = pa;
    *(float4*)(Bs + lk * 64 + lm) = bv;
    __syncthreads();
#pragma unroll
    for (int k = 0; k < 16; ++k) {
      float4 a4 = *(const float4*)(As + k * 64 + ty * 4);
      float4 b4 = *(const float4*)(Bs + k * 64 + tx * 4);
      float a[4] = {a4.x, a4.y, a4.z, a4.w};
      float b[4] = {b4.x, b4.y, b4.z, b4.w};
#pragma unroll
      for (int i = 0; i < 4; ++i)
#pragma unroll
        for (int j = 0; j < 4; ++j) acc[i][j] += a[i] * b[j];
    }
  }
#pragma unroll
  for (int i = 0; i < 4; ++i)
#pragma unroll
    for (int j = 0; j < 4; ++j)
      atomicAdd(xhat + (size_t)(s0 + ty * 4 + i) * DIM + d0 + tx * 4 + j, acc[i][j]);
}

// ---------------------------------------------------------------------------
// Expert MLP layer: Y[e*NS+p][N] = act(X[e*NS+p][:K] @ W[e][K][N] + b[e][N])
// grid (NE, N/64), block 256; 8xK slot block staged in LDS; W streamed.
// ---------------------------------------------------------------------------
template <int K, int N, bool RELU>
__global__ __launch_bounds__(256) void k_mlp(const float* __restrict__ X,
                                             const float* __restrict__ W,
                                             const float* __restrict__ bias,
                                             float* __restrict__ Y) {
  __shared__ float xs[NS * K];
  const int tid = threadIdx.x;
  const int e = blockIdx.x;
  const float4* src = (const float4*)(X + (size_t)e * NS * K);
  float4* dst = (float4*)xs;
  constexpr int NV = (NS * K) / (4 * 256);
#pragma unroll
  for (int i = 0; i < NV; ++i) dst[tid + i * 256] = src[tid + i * 256];
  __syncthreads();
  const int j = blockIdx.y * 64 + (tid & 63);
  const int pr = tid >> 6;  // handles p = pr and p = pr+4
  const float* w = W + (size_t)e * K * N + j;
  const float* x0 = xs + pr * K;
  const float* x1 = xs + (pr + 4) * K;
  float a0 = 0.f, a1 = 0.f;
#pragma unroll 8
  for (int k = 0; k < K; ++k) {
    float wv = w[(size_t)k * N];
    a0 += x0[k] * wv;
    a1 += x1[k] * wv;
  }
  const float bb = bias[(size_t)e * N + j];
  a0 += bb;
  a1 += bb;
  if (RELU) {
    a0 = fmaxf(a0, 0.f);
    a1 = fmaxf(a1, 0.f);
  }
  Y[((size_t)e * NS + pr) * N + j] = a0;
  Y[((size_t)e * NS + pr + 4) * N + j] = a1;
}

// ---------------------------------------------------------------------------
// GEMM3 (combine): out[BT][DIM] = colP @ yhat, colP[t][s] = exp(mat-m_t)*invZ_t
// applied on the fly during A staging (row-major natural).
// ---------------------------------------------------------------------------
__global__ __launch_bounds__(256) void k_gemm3(const float* __restrict__ mat,
                                               const float* __restrict__ yhat,
                                               const float* __restrict__ rowM,
                                               const float* __restrict__ rowIZ,
                                               float* __restrict__ out) {
  __shared__ float As[16 * 64];
  __shared__ float Bs[16 * 64];
  __shared__ float rm[64], rz[64];
  const int tid = threadIdx.x;
  const int t0 = blockIdx.x * 64;
  const int d0 = blockIdx.y * 64;
  if (tid < 64) {
    rm[tid] = rowM[t0 + tid];
    rz[tid] = rowIZ[t0 + tid];
  }
  const int tx = tid & 15, ty = tid >> 4;
  const int am = tid >> 2, ak = (tid & 3) * 4;
  const int bk = tid >> 4, bn = (tid & 15) * 4;
  float acc[4][4] = {};
  for (int kk = 0; kk < NP; kk += 16) {
    float4 av = *(const float4*)(mat + (size_t)(t0 + am) * NP + kk + ak);
    float4 bv = *(const float4*)(yhat + (size_t)(kk + bk) * DIM + d0 + bn);
    __syncthreads();
    const float m_ = rm[am], z_ = rz[am];
    As[(ak + 0) * 64 + am] = __expf(av.x - m_) * z_;
    As[(ak + 1) * 64 + am] = __expf(av.y - m_) * z_;
    As[(ak + 2) * 64 + am] = __expf(av.z - m_) * z_;
    As[(ak + 3) * 64 + am] = __expf(av.w - m_) * z_;
    *(float4*)(Bs + bk * 64 + bn) = bv;
    __syncthreads();
#pragma unroll
    for (int k = 0; k < 16; ++k) {
      float4 a4 = *(const float4*)(As + k * 64 + ty * 4);
      float4 b4 = *(const float4*)(Bs + k * 64 + tx * 4);
      float a[4] = {a4.x, a4.y, a4.z, a4.w};
      float b[4] = {b4.x, b4.y, b4.z, b4.w};
#pragma unroll
      for (int i = 0; i < 4; ++i)
#pragma unroll
        for (int j = 0; j < 4; ++j) acc[i][j] += a[i] * b[j];
    }
  }
#pragma unroll
  for (int i = 0; i < 4; ++i) {
    float4 o = make_float4(acc[i][0], acc[i][1], acc[i][2], acc[i][3]);
    *(float4*)(out + (size_t)(t0 + ty * 4 + i) * DIM + d0 + tx * 4) = o;
  }
}

}  // namespace

extern "C" void kernel_launch(void* const* d_in, const int* in_sizes, int n_in,
                              void* d_out, int out_size, void* d_ws, size_t ws_size,
                              hipStream_t stream) {
  const float* tokens = (const float*)d_in[0];  // [BT, DIM]
  const float* em     = (const float*)d_in[1];  // [DIM, NP]
  const float* W1     = (const float*)d_in[2];  // [NE, DIM, HID]
  const float* b1     = (const float*)d_in[3];  // [NE, HID]
  const float* W2     = (const float*)d_in[4];  // [NE, HID, HID]
  const float* b2     = (const float*)d_in[5];  // [NE, HID]
  const float* W3     = (const float*)d_in[6];  // [NE, HID, DIM]
  const float* b3     = (const float*)d_in[7];  // [NE, DIM]
  float* out = (float*)d_out;

  float* ws = (float*)d_ws;
  size_t off = 0;
  float* mat   = ws + off; off += (size_t)BT * NP;   // 64 MiB
  float* pm    = ws + off; off += (size_t)64 * NP;
  float* pz    = ws + off; off += (size_t)64 * NP;
  float* colM  = ws + off; off += NP;
  float* colIZ = ws + off; off += NP;
  float* rowM  = ws + off; off += BT;
  float* rowIZ = ws + off; off += BT;
  float* xhat  = ws + off; off += (size_t)NP * DIM;  // 2 MiB
  float* h1    = ws + off; off += (size_t)NP * HID;
  float* h2    = ws + off; off += (size_t)NP * HID;
  float* yhat  = ws + off; off += (size_t)NP * DIM;
  (void)ws_size; (void)in_sizes; (void)n_in; (void)out_size;

  // 1. routing logits
  k_gemm1<<<dim3(BT / 64, NP / 64), 256, 0, stream>>>(tokens, em, mat);
  // 2. softmax stats (columns = over tokens; rows = over slots)
  k_colpart<<<dim3(NP / 64, 64), 256, 0, stream>>>(mat, pm, pz);
  k_colfinal<<<1, NP, 0, stream>>>(pm, pz, colM, colIZ);
  k_rowstats<<<BT / 4, 256, 0, stream>>>(mat, rowM, rowIZ);
  // 3. dispatch: xhat = row_probs^T @ flat   (split-K atomics, zero first)
  hipMemsetAsync(xhat, 0, (size_t)NP * DIM * sizeof(float), stream);
  k_gemm2<<<dim3(NP / 64, DIM / 64, 32), 256, 0, stream>>>(mat, tokens, colM, colIZ, xhat);
  // 4. expert MLPs
  k_mlp<DIM, HID, true><<<dim3(NE, HID / 64), 256, 0, stream>>>(xhat, W1, b1, h1);
  k_mlp<HID, HID, true><<<dim3(NE, HID / 64), 256, 0, stream>>>(h1, W2, b2, h2);
  k_mlp<HID, DIM, false><<<dim3(NE, DIM / 64), 256, 0, stream>>>(h2, W3, b3, yhat);
  // 5. combine: out = col_probs @ yhat
  k_gemm3<<<dim3(BT / 64, DIM / 64), 256, 0, stream>>>(mat, yhat, rowM, rowIZ, out);
}

// Round 2
// 499.970 us; speedup vs baseline: 3.0998x; 3.0998x over previous
//
#include <hip/hip_runtime.h>
#include <math.h>

namespace {

constexpr int BT  = 8 * 4096;   // 32768 tokens
constexpr int DIM = 1024;       // model dim
constexpr int NE  = 64;         // experts
constexpr int NS  = 8;          // slots per expert
constexpr int NP  = NE * NS;    // 512 total slots
constexpr int HID = 256;

typedef float f32x4 __attribute__((ext_vector_type(4)));
typedef __bf16 bf16x8 __attribute__((ext_vector_type(8)));
typedef short s16x8 __attribute__((ext_vector_type(8)));

__device__ __forceinline__ ushort f2bf(float x) {
  union { float f; unsigned u; } a; a.f = x;
  unsigned r = a.u + 0x7FFFu + ((a.u >> 16) & 1u);  // RNE
  return (ushort)(r >> 16);
}

__device__ __forceinline__ void gload16(const void* g, void* l) {
  __builtin_amdgcn_global_load_lds(
      (const __attribute__((address_space(1))) void*)g,
      (__attribute__((address_space(3))) void*)l, 16, 0, 0);
}

// ---------------------------------------------------------------------------
// bf16 MFMA GEMM: C[M][N] (f32) = A[M][K](bf16 rowmajor) @ Bt[N][K](bf16)^T
// 128x128 tile, BK=32, 256 thr = 4 waves (2x2), wave = 64x64 = 4x4 frags of
// 16x16x32. global_load_lds width-16 staging, linear LDS (m97 structure).
// grid.z = split-K chunks (ATOMIC=true accumulates with atomicAdd).
// ---------------------------------------------------------------------------
template <bool ATOMIC>
__global__ __launch_bounds__(256) void k_gemm(const ushort* __restrict__ A,
                                              const ushort* __restrict__ Bt,
                                              float* __restrict__ C,
                                              int K, int N, int kchunk) {
  __shared__ __align__(16) ushort As[128 * 32];
  __shared__ __align__(16) ushort Bs[128 * 32];
  const int tid = threadIdx.x;
  const int wid = tid >> 6;
  const int lane = tid & 63;
  const int m0 = blockIdx.x * 128;
  const int n0 = blockIdx.y * 128;
  const int kb = blockIdx.z * kchunk;

  // staging: chunk c = issue*256+tid covers row c>>2, k-halfword (c&3)*8
  const int srow = tid >> 2;
  const int skoff = (tid & 3) * 8;
  ushort* asb0 = As + (size_t)(wid * 64) * 8;
  ushort* asb1 = As + (size_t)(256 + wid * 64) * 8;
  ushort* bsb0 = Bs + (size_t)(wid * 64) * 8;
  ushort* bsb1 = Bs + (size_t)(256 + wid * 64) * 8;

  const int wr = (wid >> 1) * 64;
  const int wc = (wid & 1) * 64;
  const int fr = lane & 15;
  const int fq = lane >> 4;

  f32x4 acc[4][4];
#pragma unroll
  for (int i = 0; i < 4; ++i)
#pragma unroll
    for (int j = 0; j < 4; ++j) acc[i][j] = (f32x4){0.f, 0.f, 0.f, 0.f};

  const ushort* Arow0 = A + (size_t)(m0 + srow) * K + skoff;
  const ushort* Arow1 = A + (size_t)(m0 + 64 + srow) * K + skoff;
  const ushort* Brow0 = Bt + (size_t)(n0 + srow) * K + skoff;
  const ushort* Brow1 = Bt + (size_t)(n0 + 64 + srow) * K + skoff;

  for (int kk = kb; kk < kb + kchunk; kk += 32) {
    __syncthreads();  // previous tile's ds_reads done; LDS reusable
    gload16(Arow0 + kk, asb0);
    gload16(Arow1 + kk, asb1);
    gload16(Brow0 + kk, bsb0);
    gload16(Brow1 + kk, bsb1);
    __syncthreads();  // vmcnt(0) drain -> LDS tile ready
    bf16x8 af[4], bfr[4];
#pragma unroll
    for (int m = 0; m < 4; ++m)
      af[m] = __builtin_bit_cast(
          bf16x8, *(const s16x8*)(As + (size_t)(wr + m * 16 + fr) * 32 + fq * 8));
#pragma unroll
    for (int n = 0; n < 4; ++n)
      bfr[n] = __builtin_bit_cast(
          bf16x8, *(const s16x8*)(Bs + (size_t)(wc + n * 16 + fr) * 32 + fq * 8));
#pragma unroll
    for (int m = 0; m < 4; ++m)
#pragma unroll
      for (int n = 0; n < 4; ++n)
        acc[m][n] = __builtin_amdgcn_mfma_f32_16x16x32_bf16(af[m], bfr[n], acc[m][n], 0, 0, 0);
  }

  // C/D layout: col = lane&15, row = (lane>>4)*4 + reg   [m89-verified]
  float* Cbase = C + (size_t)(m0 + wr + fq * 4) * N + n0 + wc + fr;
#pragma unroll
  for (int m = 0; m < 4; ++m)
#pragma unroll
    for (int n = 0; n < 4; ++n)
#pragma unroll
      for (int r = 0; r < 4; ++r) {
        float* p = Cbase + (size_t)(m * 16 + r) * N + n * 16;
        if (ATOMIC) atomicAdd(p, acc[m][n][r]);
        else *p = acc[m][n][r];
      }
}

// ---------------------------------------------------------------------------
// fp32 [R][C] -> bf16 rowmajor [R][C] and/or bf16 transposed [C][R], 64x64 tiles
// ---------------------------------------------------------------------------
template <bool ROWM, bool TRANSP>
__global__ __launch_bounds__(256) void k_cvt(const float* __restrict__ X,
                                             ushort* __restrict__ Yrm,
                                             ushort* __restrict__ Yt,
                                             int Rr, int Cc) {
  __shared__ ushort tT[64][68];
  const int tid = threadIdx.x;
  const int r0 = blockIdx.x * 64, c0 = blockIdx.y * 64;
#pragma unroll
  for (int i = 0; i < 4; ++i) {
    const int idx = i * 256 + tid;
    const int r = idx >> 4, c4 = (idx & 15) * 4;
    float4 v = *(const float4*)(X + (size_t)(r0 + r) * Cc + c0 + c4);
    ushort u0 = f2bf(v.x), u1 = f2bf(v.y), u2 = f2bf(v.z), u3 = f2bf(v.w);
    if (ROWM) {
      ushort4 o = make_ushort4(u0, u1, u2, u3);
      *(ushort4*)(Yrm + (size_t)(r0 + r) * Cc + c0 + c4) = o;
    }
    if (TRANSP) {
      tT[c4 + 0][r] = u0; tT[c4 + 1][r] = u1;
      tT[c4 + 2][r] = u2; tT[c4 + 3][r] = u3;
    }
  }
  if (TRANSP) {
    __syncthreads();
#pragma unroll
    for (int i = 0; i < 4; ++i) {
      const int idx = i * 256 + tid;
      const int c = idx >> 4, r4 = (idx & 15) * 4;
      ushort4 o = make_ushort4(tT[c][r4], tT[c][r4 + 1], tT[c][r4 + 2], tT[c][r4 + 3]);
      *(ushort4*)(Yt + (size_t)(c0 + c) * Rr + r0 + r4) = o;
    }
  }
}

// ---------------------------------------------------------------------------
// Probabilities in bf16: Pc[t][s] (row softmax) and Pt[s][t] (col softmax,
// transposed for K-contiguous dispatch GEMM). 64x64 tiles over mat.
// ---------------------------------------------------------------------------
__global__ __launch_bounds__(256) void k_probs(const float* __restrict__ mat,
                                               const float* __restrict__ colM,
                                               const float* __restrict__ colIZ,
                                               const float* __restrict__ rowM,
                                               const float* __restrict__ rowIZ,
                                               ushort* __restrict__ Pc,
                                               ushort* __restrict__ Pt) {
  __shared__ ushort tT[64][68];
  __shared__ float cm[64], cz[64], rm[64], rz[64];
  const int tid = threadIdx.x;
  const int t0 = blockIdx.x * 64, s0 = blockIdx.y * 64;
  if (tid < 64) {
    cm[tid] = colM[s0 + tid]; cz[tid] = colIZ[s0 + tid];
    rm[tid] = rowM[t0 + tid]; rz[tid] = rowIZ[t0 + tid];
  }
  __syncthreads();
#pragma unroll
  for (int i = 0; i < 4; ++i) {
    const int idx = i * 256 + tid;
    const int r = idx >> 4, c4 = (idx & 15) * 4;
    float4 v = *(const float4*)(mat + (size_t)(t0 + r) * NP + s0 + c4);
    const float mr = rm[r], zr = rz[r];
    ushort4 oc = make_ushort4(f2bf(__expf(v.x - mr) * zr), f2bf(__expf(v.y - mr) * zr),
                              f2bf(__expf(v.z - mr) * zr), f2bf(__expf(v.w - mr) * zr));
    *(ushort4*)(Pc + (size_t)(t0 + r) * NP + s0 + c4) = oc;
    tT[c4 + 0][r] = f2bf(__expf(v.x - cm[c4 + 0]) * cz[c4 + 0]);
    tT[c4 + 1][r] = f2bf(__expf(v.y - cm[c4 + 1]) * cz[c4 + 1]);
    tT[c4 + 2][r] = f2bf(__expf(v.z - cm[c4 + 2]) * cz[c4 + 2]);
    tT[c4 + 3][r] = f2bf(__expf(v.w - cm[c4 + 3]) * cz[c4 + 3]);
  }
  __syncthreads();
#pragma unroll
  for (int i = 0; i < 4; ++i) {
    const int idx = i * 256 + tid;
    const int c = idx >> 4, r4 = (idx & 15) * 4;
    ushort4 o = make_ushort4(tT[c][r4], tT[c][r4 + 1], tT[c][r4 + 2], tT[c][r4 + 3]);
    *(ushort4*)(Pt + (size_t)(s0 + c) * BT + t0 + r4) = o;
  }
}

// ---------------------------------------------------------------------------
// Column softmax stats (over tokens) — unchanged from round 1
// ---------------------------------------------------------------------------
__global__ __launch_bounds__(256) void k_colpart(const float* __restrict__ mat,
                                                 float* __restrict__ pm,
                                                 float* __restrict__ pz) {
  const int col = blockIdx.x * 64 + (threadIdx.x & 63);
  const int tyy = threadIdx.x >> 6;
  const int r0 = blockIdx.y * 512;
  float m = -INFINITY, z = 0.f;
  for (int r = r0 + tyy; r < r0 + 512; r += 4) {
    float v = mat[(size_t)r * NP + col];
    if (v <= m) {
      z += __expf(v - m);
    } else {
      z = z * __expf(m - v) + 1.f;
      m = v;
    }
  }
  __shared__ float smx[256], szx[256];
  smx[threadIdx.x] = m;
  szx[threadIdx.x] = z;
  __syncthreads();
  if (tyy == 0) {
    for (int q = 1; q < 4; ++q) {
      float m2 = smx[threadIdx.x + q * 64], z2 = szx[threadIdx.x + q * 64];
      float mm = fmaxf(m, m2);
      z = z * __expf(m - mm) + z2 * __expf(m2 - mm);
      m = mm;
    }
    pm[(size_t)blockIdx.y * NP + col] = m;
    pz[(size_t)blockIdx.y * NP + col] = z;
  }
}

__global__ void k_colfinal(const float* __restrict__ pm, const float* __restrict__ pz,
                           float* __restrict__ colM, float* __restrict__ colIZ) {
  const int c = threadIdx.x;  // <<<1, NP>>>
  float m = -INFINITY, z = 0.f;
  for (int q = 0; q < 64; ++q) {
    float m2 = pm[(size_t)q * NP + c], z2 = pz[(size_t)q * NP + c];
    float mm = fmaxf(m, m2);
    z = z * __expf(m - mm) + z2 * __expf(m2 - mm);
    m = mm;
  }
  colM[c] = m;
  colIZ[c] = 1.f / z;
}

__global__ __launch_bounds__(256) void k_rowstats(const float* __restrict__ mat,
                                                  float* __restrict__ rowM,
                                                  float* __restrict__ rowIZ) {
  const int w = threadIdx.x >> 6;
  const int lane = threadIdx.x & 63;
  const int t = blockIdx.x * 4 + w;
  const float4* row = (const float4*)(mat + (size_t)t * NP);
  float4 v1 = row[lane];
  float4 v2 = row[lane + 64];
  float m = fmaxf(fmaxf(fmaxf(v1.x, v1.y), fmaxf(v1.z, v1.w)),
                  fmaxf(fmaxf(v2.x, v2.y), fmaxf(v2.z, v2.w)));
#pragma unroll
  for (int o = 32; o; o >>= 1) m = fmaxf(m, __shfl_xor(m, o));
  float s = __expf(v1.x - m) + __expf(v1.y - m) + __expf(v1.z - m) + __expf(v1.w - m) +
            __expf(v2.x - m) + __expf(v2.y - m) + __expf(v2.z - m) + __expf(v2.w - m);
#pragma unroll
  for (int o = 32; o; o >>= 1) s += __shfl_xor(s, o);
  if (lane == 0) {
    rowM[t] = m;
    rowIZ[t] = 1.f / s;
  }
}

// ---------------------------------------------------------------------------
// Expert MLP layer (fp32, weight-streaming, memory-bound) — unchanged
// ---------------------------------------------------------------------------
template <int K, int N, bool RELU>
__global__ __launch_bounds__(256) void k_mlp(const float* __restrict__ X,
                                             const float* __restrict__ W,
                                             const float* __restrict__ bias,
                                             float* __restrict__ Y) {
  __shared__ float xs[NS * K];
  const int tid = threadIdx.x;
  const int e = blockIdx.x;
  const float4* src = (const float4*)(X + (size_t)e * NS * K);
  float4* dst = (float4*)xs;
  constexpr int NV = (NS * K) / (4 * 256);
#pragma unroll
  for (int i = 0; i < NV; ++i) dst[tid + i * 256] = src[tid + i * 256];
  __syncthreads();
  const int j = blockIdx.y * 64 + (tid & 63);
  const int pr = tid >> 6;
  const float* w = W + (size_t)e * K * N + j;
  const float* x0 = xs + pr * K;
  const float* x1 = xs + (pr + 4) * K;
  float a0 = 0.f, a1 = 0.f;
#pragma unroll 8
  for (int k = 0; k < K; ++k) {
    float wv = w[(size_t)k * N];
    a0 += x0[k] * wv;
    a1 += x1[k] * wv;
  }
  const float bb = bias[(size_t)e * N + j];
  a0 += bb;
  a1 += bb;
  if (RELU) {
    a0 = fmaxf(a0, 0.f);
    a1 = fmaxf(a1, 0.f);
  }
  Y[((size_t)e * NS + pr) * N + j] = a0;
  Y[((size_t)e * NS + pr + 4) * N + j] = a1;
}

}  // namespace

extern "C" void kernel_launch(void* const* d_in, const int* in_sizes, int n_in,
                              void* d_out, int out_size, void* d_ws, size_t ws_size,
                              hipStream_t stream) {
  const float* tokens = (const float*)d_in[0];  // [BT, DIM]
  const float* em     = (const float*)d_in[1];  // [DIM, NP]
  const float* W1     = (const float*)d_in[2];
  const float* b1     = (const float*)d_in[3];
  const float* W2     = (const float*)d_in[4];
  const float* b2     = (const float*)d_in[5];
  const float* W3     = (const float*)d_in[6];
  const float* b3     = (const float*)d_in[7];
  float* out = (float*)d_out;

  char* w = (char*)d_ws;
  float*  mat       = (float*)w;                 // [BT][NP] fp32, 64MB
  ushort* tokT      = (ushort*)w;                // [DIM][BT] bf16 (aliases mat; mat dead by then)
  w += (size_t)BT * NP * 4;
  ushort* tokens_bf = (ushort*)w; w += (size_t)BT * DIM * 2;   // 64MB
  ushort* Pt        = (ushort*)w; w += (size_t)NP * BT * 2;    // 33.5MB
  ushort* Pc        = (ushort*)w; w += (size_t)BT * NP * 2;    // 33.5MB
  ushort* emT       = (ushort*)w; w += (size_t)NP * DIM * 2;   // 1MB
  ushort* yhatT     = (ushort*)w; w += (size_t)DIM * NP * 2;   // 1MB
  float*  pm        = (float*)w;  w += (size_t)64 * NP * 4;
  float*  pz        = (float*)w;  w += (size_t)64 * NP * 4;
  float*  colM      = (float*)w;  w += NP * 4;
  float*  colIZ     = (float*)w;  w += NP * 4;
  float*  rowM      = (float*)w;  w += BT * 4;
  float*  rowIZ     = (float*)w;  w += BT * 4;
  float*  xhat      = (float*)w;  w += (size_t)NP * DIM * 4;   // 2MB
  float*  h1        = (float*)w;  w += (size_t)NP * HID * 4;
  float*  h2        = (float*)w;  w += (size_t)NP * HID * 4;
  float*  yhat      = (float*)w;  w += (size_t)NP * DIM * 4;
  (void)ws_size; (void)in_sizes; (void)n_in; (void)out_size;

  // prep: bf16 operands (K-contiguous forms)
  k_cvt<true, false><<<dim3(BT / 64, DIM / 64), 256, 0, stream>>>(tokens, tokens_bf, nullptr, BT, DIM);
  k_cvt<false, true><<<dim3(DIM / 64, NP / 64), 256, 0, stream>>>(em, nullptr, emT, DIM, NP);
  // 1. routing logits: mat = tokens @ em   (MFMA)
  k_gemm<false><<<dim3(BT / 128, NP / 128, 1), 256, 0, stream>>>(tokens_bf, emT, mat, DIM, NP, DIM);
  // 2. softmax stats
  k_colpart<<<dim3(NP / 64, 64), 256, 0, stream>>>(mat, pm, pz);
  k_colfinal<<<1, NP, 0, stream>>>(pm, pz, colM, colIZ);
  k_rowstats<<<BT / 4, 256, 0, stream>>>(mat, rowM, rowIZ);
  // 3. probabilities in bf16 (Pt transposed); then tokens^T (reuses mat buffer)
  k_probs<<<dim3(BT / 64, NP / 64), 256, 0, stream>>>(mat, colM, colIZ, rowM, rowIZ, Pc, Pt);
  k_cvt<false, true><<<dim3(BT / 64, DIM / 64), 256, 0, stream>>>(tokens, nullptr, tokT, BT, DIM);
  // 4. dispatch: xhat = Pt @ tokens  (split-K 32, fp32 atomics)
  hipMemsetAsync(xhat, 0, (size_t)NP * DIM * 4, stream);
  k_gemm<true><<<dim3(NP / 128, DIM / 128, 32), 256, 0, stream>>>(Pt, tokT, xhat, BT, DIM, BT / 32);
  // 5. expert MLPs (fp32)
  k_mlp<DIM, HID, true><<<dim3(NE, HID / 64), 256, 0, stream>>>(xhat, W1, b1, h1);
  k_mlp<HID, HID, true><<<dim3(NE, HID / 64), 256, 0, stream>>>(h1, W2, b2, h2);
  k_mlp<HID, DIM, false><<<dim3(NE, DIM / 64), 256, 0, stream>>>(h2, W3, b3, yhat);
  k_cvt<false, true><<<dim3(NP / 64, DIM / 64), 256, 0, stream>>>(yhat, nullptr, yhatT, NP, DIM);
  // 6. combine: out = Pc @ yhat   (MFMA)
  k_gemm<false><<<dim3(BT / 128, DIM / 128, 1), 256, 0, stream>>>(Pc, yhatT, out, NP, DIM, NP);
}

// Round 3
// 460.689 us; speedup vs baseline: 3.3641x; 1.0853x over previous
//
#include <hip/hip_runtime.h>
#include <math.h>

namespace {

constexpr int BT  = 8 * 4096;   // 32768 tokens
constexpr int DIM = 1024;       // model dim
constexpr int NE  = 64;         // experts
constexpr int NS  = 8;          // slots per expert
constexpr int NP  = NE * NS;    // 512 total slots
constexpr int HID = 256;

typedef float f32x4 __attribute__((ext_vector_type(4)));
typedef __bf16 bf16x8 __attribute__((ext_vector_type(8)));
typedef short s16x8 __attribute__((ext_vector_type(8)));

__device__ __forceinline__ ushort f2bf(float x) {
  union { float f; unsigned u; } a; a.f = x;
  unsigned r = a.u + 0x7FFFu + ((a.u >> 16) & 1u);  // RNE
  return (ushort)(r >> 16);
}
__device__ __forceinline__ float bf2f(ushort u) {
  union { unsigned u; float f; } a; a.u = (unsigned)u << 16;
  return a.f;
}

__device__ __forceinline__ void gload16(const void* g, void* l) {
  __builtin_amdgcn_global_load_lds(
      (const __attribute__((address_space(1))) void*)g,
      (__attribute__((address_space(3))) void*)l, 16, 0, 0);
}

// ---------------------------------------------------------------------------
// bf16 MFMA GEMM: C[M][N] = A[M][K](bf16 rm) @ Bt[N][K](bf16)^T
// 128x128 tile, BK=32, 4 waves 2x2 (m97 structure). grid: x=N-blk, y=M-blk,
// z=split-K. Consecutive x-blocks share the A panel -> L2 hits.
// OBF: write bf16; ATOMIC: fp32 atomicAdd accumulate.
// ---------------------------------------------------------------------------
template <bool ATOMIC, bool OBF>
__global__ __launch_bounds__(256) void k_gemm(const ushort* __restrict__ A,
                                              const ushort* __restrict__ Bt,
                                              void* __restrict__ Cv,
                                              int K, int N, int kchunk) {
  __shared__ __align__(16) ushort As[128 * 32];
  __shared__ __align__(16) ushort Bs[128 * 32];
  const int tid = threadIdx.x;
  const int wid = tid >> 6;
  const int lane = tid & 63;
  const int n0 = blockIdx.x * 128;
  const int m0 = blockIdx.y * 128;
  const int kb = blockIdx.z * kchunk;

  const int srow = tid >> 2;
  const int skoff = (tid & 3) * 8;
  ushort* asb0 = As + (size_t)(wid * 64) * 8;
  ushort* asb1 = As + (size_t)(256 + wid * 64) * 8;
  ushort* bsb0 = Bs + (size_t)(wid * 64) * 8;
  ushort* bsb1 = Bs + (size_t)(256 + wid * 64) * 8;

  const int wr = (wid >> 1) * 64;
  const int wc = (wid & 1) * 64;
  const int fr = lane & 15;
  const int fq = lane >> 4;

  f32x4 acc[4][4];
#pragma unroll
  for (int i = 0; i < 4; ++i)
#pragma unroll
    for (int j = 0; j < 4; ++j) acc[i][j] = (f32x4){0.f, 0.f, 0.f, 0.f};

  const ushort* Arow0 = A + (size_t)(m0 + srow) * K + skoff;
  const ushort* Arow1 = A + (size_t)(m0 + 64 + srow) * K + skoff;
  const ushort* Brow0 = Bt + (size_t)(n0 + srow) * K + skoff;
  const ushort* Brow1 = Bt + (size_t)(n0 + 64 + srow) * K + skoff;

  for (int kk = kb; kk < kb + kchunk; kk += 32) {
    __syncthreads();
    gload16(Arow0 + kk, asb0);
    gload16(Arow1 + kk, asb1);
    gload16(Brow0 + kk, bsb0);
    gload16(Brow1 + kk, bsb1);
    __syncthreads();
    bf16x8 af[4], bfr[4];
#pragma unroll
    for (int m = 0; m < 4; ++m)
      af[m] = __builtin_bit_cast(
          bf16x8, *(const s16x8*)(As + (size_t)(wr + m * 16 + fr) * 32 + fq * 8));
#pragma unroll
    for (int n = 0; n < 4; ++n)
      bfr[n] = __builtin_bit_cast(
          bf16x8, *(const s16x8*)(Bs + (size_t)(wc + n * 16 + fr) * 32 + fq * 8));
#pragma unroll
    for (int m = 0; m < 4; ++m)
#pragma unroll
      for (int n = 0; n < 4; ++n)
        acc[m][n] = __builtin_amdgcn_mfma_f32_16x16x32_bf16(af[m], bfr[n], acc[m][n], 0, 0, 0);
  }

  // C/D layout: col = lane&15, row = (lane>>4)*4 + reg   [m89-verified]
  if (OBF) {
    ushort* Cb = (ushort*)Cv + (size_t)(m0 + wr + fq * 4) * N + n0 + wc + fr;
#pragma unroll
    for (int m = 0; m < 4; ++m)
#pragma unroll
      for (int n = 0; n < 4; ++n)
#pragma unroll
        for (int r = 0; r < 4; ++r)
          Cb[(size_t)(m * 16 + r) * N + n * 16] = f2bf(acc[m][n][r]);
  } else {
    float* Cb = (float*)Cv + (size_t)(m0 + wr + fq * 4) * N + n0 + wc + fr;
#pragma unroll
    for (int m = 0; m < 4; ++m)
#pragma unroll
      for (int n = 0; n < 4; ++n)
#pragma unroll
        for (int r = 0; r < 4; ++r) {
          float* p = Cb + (size_t)(m * 16 + r) * N + n * 16;
          if (ATOMIC) atomicAdd(p, acc[m][n][r]);
          else *p = acc[m][n][r];
        }
  }
}

// ---------------------------------------------------------------------------
// fp32 [R][C] -> bf16 rowmajor and/or bf16 transposed, 64x64 tiles
// ---------------------------------------------------------------------------
template <bool ROWM, bool TRANSP>
__global__ __launch_bounds__(256) void k_cvt(const float* __restrict__ X,
                                             ushort* __restrict__ Yrm,
                                             ushort* __restrict__ Yt,
                                             int Rr, int Cc) {
  __shared__ ushort tT[64][66];
  const int tid = threadIdx.x;
  const int r0 = blockIdx.x * 64, c0 = blockIdx.y * 64;
#pragma unroll
  for (int i = 0; i < 4; ++i) {
    const int idx = i * 256 + tid;
    const int r = idx >> 4, c4 = (idx & 15) * 4;
    float4 v = *(const float4*)(X + (size_t)(r0 + r) * Cc + c0 + c4);
    ushort u0 = f2bf(v.x), u1 = f2bf(v.y), u2 = f2bf(v.z), u3 = f2bf(v.w);
    if (ROWM) {
      ushort4 o = make_ushort4(u0, u1, u2, u3);
      *(ushort4*)(Yrm + (size_t)(r0 + r) * Cc + c0 + c4) = o;
    }
    if (TRANSP) {
      tT[c4 + 0][r] = u0; tT[c4 + 1][r] = u1;
      tT[c4 + 2][r] = u2; tT[c4 + 3][r] = u3;
    }
  }
  if (TRANSP) {
    __syncthreads();
#pragma unroll
    for (int i = 0; i < 4; ++i) {
      const int idx = i * 256 + tid;
      const int c = idx >> 4, r4 = (idx & 15) * 4;
      ushort4 o = make_ushort4(tT[c][r4], tT[c][r4 + 1], tT[c][r4 + 2], tT[c][r4 + 3]);
      *(ushort4*)(Yt + (size_t)(c0 + c) * Rr + r0 + r4) = o;
    }
  }
}

// ---------------------------------------------------------------------------
// Column softmax stats over bf16 mat. Block: 256 rows x all 512 cols.
// thread covers 8 cols ((tid&63)*8), row-stride 4. ushort8 coalesced loads.
// ---------------------------------------------------------------------------
__global__ __launch_bounds__(256) void k_colpart(const ushort* __restrict__ mat,
                                                 float* __restrict__ pm,
                                                 float* __restrict__ pz) {
  const int c8 = (threadIdx.x & 63) * 8;
  const int rq = threadIdx.x >> 6;
  const int r0 = blockIdx.x * 256;
  float m[8], z[8];
#pragma unroll
  for (int j = 0; j < 8; ++j) { m[j] = -INFINITY; z[j] = 0.f; }
  for (int r = r0 + rq; r < r0 + 256; r += 4) {
    s16x8 v = *(const s16x8*)(mat + (size_t)r * NP + c8);
#pragma unroll
    for (int j = 0; j < 8; ++j) {
      float f = bf2f((ushort)v[j]);
      float mm = fmaxf(m[j], f);
      z[j] = z[j] * __expf(m[j] - mm) + __expf(f - mm);
      m[j] = mm;
    }
  }
  __shared__ float sm[4][NP], sz[4][NP];
#pragma unroll
  for (int j = 0; j < 8; ++j) { sm[rq][c8 + j] = m[j]; sz[rq][c8 + j] = z[j]; }
  __syncthreads();
  if (rq == 0) {
#pragma unroll
    for (int j = 0; j < 8; ++j) {
      float mj = m[j], zj = z[j];
      for (int q = 1; q < 4; ++q) {
        float m2 = sm[q][c8 + j], z2 = sz[q][c8 + j];
        float mm = fmaxf(mj, m2);
        zj = zj * __expf(mj - mm) + z2 * __expf(m2 - mm);
        mj = mm;
      }
      pm[(size_t)blockIdx.x * NP + c8 + j] = mj;
      pz[(size_t)blockIdx.x * NP + c8 + j] = zj;
    }
  }
}

__global__ void k_colfinal(const float* __restrict__ pm, const float* __restrict__ pz,
                           float* __restrict__ colM, float* __restrict__ colIZ) {
  const int c = threadIdx.x;  // <<<1, NP>>>
  float m = -INFINITY, z = 0.f;
  for (int q = 0; q < BT / 256; ++q) {
    float m2 = pm[(size_t)q * NP + c], z2 = pz[(size_t)q * NP + c];
    float mm = fmaxf(m, m2);
    z = z * __expf(m - mm) + z2 * __expf(m2 - mm);
    m = mm;
  }
  colM[c] = m;
  colIZ[c] = 1.f / z;
}

// ---------------------------------------------------------------------------
// Row softmax stats over bf16 mat: one wave per token, ushort8 per lane.
// ---------------------------------------------------------------------------
__global__ __launch_bounds__(256) void k_rowstats(const ushort* __restrict__ mat,
                                                  float* __restrict__ rowM,
                                                  float* __restrict__ rowIZ) {
  const int w = threadIdx.x >> 6;
  const int lane = threadIdx.x & 63;
  const int t = blockIdx.x * 4 + w;
  s16x8 v = *(const s16x8*)(mat + (size_t)t * NP + lane * 8);
  float f[8];
#pragma unroll
  for (int j = 0; j < 8; ++j) f[j] = bf2f((ushort)v[j]);
  float m = f[0];
#pragma unroll
  for (int j = 1; j < 8; ++j) m = fmaxf(m, f[j]);
#pragma unroll
  for (int o = 32; o; o >>= 1) m = fmaxf(m, __shfl_xor(m, o));
  float s = 0.f;
#pragma unroll
  for (int j = 0; j < 8; ++j) s += __expf(f[j] - m);
#pragma unroll
  for (int o = 32; o; o >>= 1) s += __shfl_xor(s, o);
  if (lane == 0) {
    rowM[t] = m;
    rowIZ[t] = 1.f / s;
  }
}

// ---------------------------------------------------------------------------
// Probabilities in bf16 from bf16 mat: Pc[t][s] (row softmax) and
// Pt[s][t] (col softmax, transposed). 64x64 tiles.
// ---------------------------------------------------------------------------
__global__ __launch_bounds__(256) void k_probs(const ushort* __restrict__ mat,
                                               const float* __restrict__ colM,
                                               const float* __restrict__ colIZ,
                                               const float* __restrict__ rowM,
                                               const float* __restrict__ rowIZ,
                                               ushort* __restrict__ Pc,
                                               ushort* __restrict__ Pt) {
  __shared__ ushort tT[64][66];
  __shared__ float cm[64], cz[64], rm[64], rz[64];
  const int tid = threadIdx.x;
  const int t0 = blockIdx.x * 64, s0 = blockIdx.y * 64;
  if (tid < 64) {
    cm[tid] = colM[s0 + tid]; cz[tid] = colIZ[s0 + tid];
    rm[tid] = rowM[t0 + tid]; rz[tid] = rowIZ[t0 + tid];
  }
  __syncthreads();
#pragma unroll
  for (int i = 0; i < 2; ++i) {
    const int idx = i * 256 + tid;
    const int r = idx >> 3, c8 = (idx & 7) * 8;
    s16x8 v = *(const s16x8*)(mat + (size_t)(t0 + r) * NP + s0 + c8);
    const float mr = rm[r], zr = rz[r];
    s16x8 oc;
#pragma unroll
    for (int j = 0; j < 8; ++j) {
      float f = bf2f((ushort)v[j]);
      oc[j] = (short)f2bf(__expf(f - mr) * zr);
      tT[c8 + j][r] = f2bf(__expf(f - cm[c8 + j]) * cz[c8 + j]);
    }
    *(s16x8*)(Pc + (size_t)(t0 + r) * NP + s0 + c8) = oc;
  }
  __syncthreads();
#pragma unroll
  for (int i = 0; i < 2; ++i) {
    const int idx = i * 256 + tid;
    const int c = idx >> 3, r8 = (idx & 7) * 8;
    s16x8 o;
#pragma unroll
    for (int j = 0; j < 8; ++j) o[j] = (short)tT[c][r8 + j];
    *(s16x8*)(Pt + (size_t)(s0 + c) * BT + t0 + r8) = o;
  }
}

// ---------------------------------------------------------------------------
// Expert MLP layer (fp32, weight-streaming, memory-bound)
// ---------------------------------------------------------------------------
template <int K, int N, bool RELU>
__global__ __launch_bounds__(256) void k_mlp(const float* __restrict__ X,
                                             const float* __restrict__ W,
                                             const float* __restrict__ bias,
                                             float* __restrict__ Y) {
  __shared__ float xs[NS * K];
  const int tid = threadIdx.x;
  const int e = blockIdx.x;
  const float4* src = (const float4*)(X + (size_t)e * NS * K);
  float4* dst = (float4*)xs;
  constexpr int NV = (NS * K) / (4 * 256);
#pragma unroll
  for (int i = 0; i < NV; ++i) dst[tid + i * 256] = src[tid + i * 256];
  __syncthreads();
  const int j = blockIdx.y * 64 + (tid & 63);
  const int pr = tid >> 6;
  const float* w = W + (size_t)e * K * N + j;
  const float* x0 = xs + pr * K;
  const float* x1 = xs + (pr + 4) * K;
  float a0 = 0.f, a1 = 0.f;
#pragma unroll 8
  for (int k = 0; k < K; ++k) {
    float wv = w[(size_t)k * N];
    a0 += x0[k] * wv;
    a1 += x1[k] * wv;
  }
  const float bb = bias[(size_t)e * N + j];
  a0 += bb;
  a1 += bb;
  if (RELU) {
    a0 = fmaxf(a0, 0.f);
    a1 = fmaxf(a1, 0.f);
  }
  Y[((size_t)e * NS + pr) * N + j] = a0;
  Y[((size_t)e * NS + pr + 4) * N + j] = a1;
}

}  // namespace

extern "C" void kernel_launch(void* const* d_in, const int* in_sizes, int n_in,
                              void* d_out, int out_size, void* d_ws, size_t ws_size,
                              hipStream_t stream) {
  const float* tokens = (const float*)d_in[0];  // [BT, DIM]
  const float* em     = (const float*)d_in[1];  // [DIM, NP]
  const float* W1     = (const float*)d_in[2];
  const float* b1     = (const float*)d_in[3];
  const float* W2     = (const float*)d_in[4];
  const float* b2     = (const float*)d_in[5];
  const float* W3     = (const float*)d_in[6];
  const float* b3     = (const float*)d_in[7];
  float* out = (float*)d_out;

  char* w = (char*)d_ws;
  ushort* matb      = (ushort*)w; w += (size_t)BT * NP * 2;    // 32MB bf16 logits
  ushort* tokens_bf = (ushort*)w; w += (size_t)BT * DIM * 2;   // 64MB
  ushort* tokT      = (ushort*)w; w += (size_t)DIM * BT * 2;   // 64MB
  ushort* Pt        = (ushort*)w; w += (size_t)NP * BT * 2;    // 33.5MB
  ushort* Pc        = (ushort*)w; w += (size_t)BT * NP * 2;    // 33.5MB
  ushort* emT       = (ushort*)w; w += (size_t)NP * DIM * 2;
  ushort* yhatT     = (ushort*)w; w += (size_t)DIM * NP * 2;
  float*  pm        = (float*)w;  w += (size_t)(BT / 256) * NP * 4;
  float*  pz        = (float*)w;  w += (size_t)(BT / 256) * NP * 4;
  float*  colM      = (float*)w;  w += NP * 4;
  float*  colIZ     = (float*)w;  w += NP * 4;
  float*  rowM      = (float*)w;  w += BT * 4;
  float*  rowIZ     = (float*)w;  w += BT * 4;
  float*  xhat      = (float*)w;  w += (size_t)NP * DIM * 4;
  float*  h1        = (float*)w;  w += (size_t)NP * HID * 4;
  float*  h2        = (float*)w;  w += (size_t)NP * HID * 4;
  float*  yhat      = (float*)w;  w += (size_t)NP * DIM * 4;
  (void)ws_size; (void)in_sizes; (void)n_in; (void)out_size;

  // prep: one pass over fp32 tokens -> rowmajor bf16 + transposed bf16
  k_cvt<true, true><<<dim3(BT / 64, DIM / 64), 256, 0, stream>>>(tokens, tokens_bf, tokT, BT, DIM);
  k_cvt<false, true><<<dim3(DIM / 64, NP / 64), 256, 0, stream>>>(em, nullptr, emT, DIM, NP);
  // 1. routing logits (bf16 out): grid x=N-blocks for A-panel L2 reuse
  k_gemm<false, true><<<dim3(NP / 128, BT / 128, 1), 256, 0, stream>>>(tokens_bf, emT, matb, DIM, NP, DIM);
  // 2. softmax stats
  k_colpart<<<BT / 256, 256, 0, stream>>>(matb, pm, pz);
  k_colfinal<<<1, NP, 0, stream>>>(pm, pz, colM, colIZ);
  k_rowstats<<<BT / 4, 256, 0, stream>>>(matb, rowM, rowIZ);
  // 3. probabilities in bf16 (Pc rowmajor, Pt transposed)
  k_probs<<<dim3(BT / 64, NP / 64), 256, 0, stream>>>(matb, colM, colIZ, rowM, rowIZ, Pc, Pt);
  // 4. dispatch: xhat = Pt @ tokens  (split-K 16, fp32 atomics)
  hipMemsetAsync(xhat, 0, (size_t)NP * DIM * 4, stream);
  k_gemm<true, false><<<dim3(DIM / 128, NP / 128, 16), 256, 0, stream>>>(Pt, tokT, xhat, BT, DIM, BT / 16);
  // 5. expert MLPs (fp32)
  k_mlp<DIM, HID, true><<<dim3(NE, HID / 64), 256, 0, stream>>>(xhat, W1, b1, h1);
  k_mlp<HID, HID, true><<<dim3(NE, HID / 64), 256, 0, stream>>>(h1, W2, b2, h2);
  k_mlp<HID, DIM, false><<<dim3(NE, DIM / 64), 256, 0, stream>>>(h2, W3, b3, yhat);
  k_cvt<false, true><<<dim3(NP / 64, DIM / 64), 256, 0, stream>>>(yhat, nullptr, yhatT, NP, DIM);
  // 6. combine: out = Pc @ yhat
  k_gemm<false, false><<<dim3(DIM / 128, BT / 128, 1), 256, 0, stream>>>(Pc, yhatT, out, NP, DIM, NP);
}

// Round 4
// 452.024 us; speedup vs baseline: 3.4286x; 1.0192x over previous
//
#include <hip/hip_runtime.h>
#include <math.h>

namespace {

constexpr int BT  = 8 * 4096;   // 32768 tokens
constexpr int DIM = 1024;       // model dim
constexpr int NE  = 64;         // experts
constexpr int NS  = 8;          // slots per expert
constexpr int NP  = NE * NS;    // 512 total slots
constexpr int HID = 256;

typedef float f32x4 __attribute__((ext_vector_type(4)));
typedef __bf16 bf16x8 __attribute__((ext_vector_type(8)));
typedef short s16x8 __attribute__((ext_vector_type(8)));

__device__ __forceinline__ ushort f2bf(float x) {
  union { float f; unsigned u; } a; a.f = x;
  unsigned r = a.u + 0x7FFFu + ((a.u >> 16) & 1u);  // RNE
  return (ushort)(r >> 16);
}
__device__ __forceinline__ float bf2f(ushort u) {
  union { unsigned u; float f; } a; a.u = (unsigned)u << 16;
  return a.f;
}

__device__ __forceinline__ void gload16(const void* g, void* l) {
  __builtin_amdgcn_global_load_lds(
      (const __attribute__((address_space(1))) void*)g,
      (__attribute__((address_space(3))) void*)l, 16, 0, 0);
}

// ---------------------------------------------------------------------------
// bf16 MFMA GEMM: C[M][N] = A[M][K](bf16 rm) @ Bt[N][K](bf16)^T
// 128x128 tile, BK=32, 4 waves 2x2 (m97 structure).
// T1: bijective chunked XCD swizzle over the full 3D linear wg id — each XCD
// gets a contiguous chunk, so blocks sharing an A-panel hit the same L2.
// Requires total nwg % 8 == 0 (all our launches satisfy this).
// ---------------------------------------------------------------------------
template <bool ATOMIC, bool OBF>
__global__ __launch_bounds__(256) void k_gemm(const ushort* __restrict__ A,
                                              const ushort* __restrict__ Bt,
                                              void* __restrict__ Cv,
                                              int K, int N, int kchunk) {
  __shared__ __align__(16) ushort As[128 * 32];
  __shared__ __align__(16) ushort Bs[128 * 32];
  const int tid = threadIdx.x;
  const int wid = tid >> 6;
  const int lane = tid & 63;

  // T1 XCD-chunked swizzle (bijective: nwg % 8 == 0)
  const int gx = gridDim.x, gy = gridDim.y;
  int wg = (blockIdx.z * gy + blockIdx.y) * gx + blockIdx.x;
  const int nwg = gx * gy * gridDim.z;
  wg = (wg & 7) * (nwg >> 3) + (wg >> 3);
  const int bx = wg % gx;
  const int rest = wg / gx;
  const int by = rest % gy;
  const int bz = rest / gy;

  const int n0 = bx * 128;
  const int m0 = by * 128;
  const int kb = bz * kchunk;

  const int srow = tid >> 2;
  const int skoff = (tid & 3) * 8;
  ushort* asb0 = As + (size_t)(wid * 64) * 8;
  ushort* asb1 = As + (size_t)(256 + wid * 64) * 8;
  ushort* bsb0 = Bs + (size_t)(wid * 64) * 8;
  ushort* bsb1 = Bs + (size_t)(256 + wid * 64) * 8;

  const int wr = (wid >> 1) * 64;
  const int wc = (wid & 1) * 64;
  const int fr = lane & 15;
  const int fq = lane >> 4;

  f32x4 acc[4][4];
#pragma unroll
  for (int i = 0; i < 4; ++i)
#pragma unroll
    for (int j = 0; j < 4; ++j) acc[i][j] = (f32x4){0.f, 0.f, 0.f, 0.f};

  const ushort* Arow0 = A + (size_t)(m0 + srow) * K + skoff;
  const ushort* Arow1 = A + (size_t)(m0 + 64 + srow) * K + skoff;
  const ushort* Brow0 = Bt + (size_t)(n0 + srow) * K + skoff;
  const ushort* Brow1 = Bt + (size_t)(n0 + 64 + srow) * K + skoff;

  for (int kk = kb; kk < kb + kchunk; kk += 32) {
    __syncthreads();
    gload16(Arow0 + kk, asb0);
    gload16(Arow1 + kk, asb1);
    gload16(Brow0 + kk, bsb0);
    gload16(Brow1 + kk, bsb1);
    __syncthreads();
    bf16x8 af[4], bfr[4];
#pragma unroll
    for (int m = 0; m < 4; ++m)
      af[m] = __builtin_bit_cast(
          bf16x8, *(const s16x8*)(As + (size_t)(wr + m * 16 + fr) * 32 + fq * 8));
#pragma unroll
    for (int n = 0; n < 4; ++n)
      bfr[n] = __builtin_bit_cast(
          bf16x8, *(const s16x8*)(Bs + (size_t)(wc + n * 16 + fr) * 32 + fq * 8));
#pragma unroll
    for (int m = 0; m < 4; ++m)
#pragma unroll
      for (int n = 0; n < 4; ++n)
        acc[m][n] = __builtin_amdgcn_mfma_f32_16x16x32_bf16(af[m], bfr[n], acc[m][n], 0, 0, 0);
  }

  // C/D layout: col = lane&15, row = (lane>>4)*4 + reg   [m89-verified]
  if (OBF) {
    ushort* Cb = (ushort*)Cv + (size_t)(m0 + wr + fq * 4) * N + n0 + wc + fr;
#pragma unroll
    for (int m = 0; m < 4; ++m)
#pragma unroll
      for (int n = 0; n < 4; ++n)
#pragma unroll
        for (int r = 0; r < 4; ++r)
          Cb[(size_t)(m * 16 + r) * N + n * 16] = f2bf(acc[m][n][r]);
  } else {
    float* Cb = (float*)Cv + (size_t)(m0 + wr + fq * 4) * N + n0 + wc + fr;
#pragma unroll
    for (int m = 0; m < 4; ++m)
#pragma unroll
      for (int n = 0; n < 4; ++n)
#pragma unroll
        for (int r = 0; r < 4; ++r) {
          float* p = Cb + (size_t)(m * 16 + r) * N + n * 16;
          if (ATOMIC) atomicAdd(p, acc[m][n][r]);
          else *p = acc[m][n][r];
        }
  }
}

// ---------------------------------------------------------------------------
// fp32 [R][C] -> bf16 rowmajor and/or bf16 transposed, 64x64 tiles
// ---------------------------------------------------------------------------
template <bool ROWM, bool TRANSP>
__global__ __launch_bounds__(256) void k_cvt(const float* __restrict__ X,
                                             ushort* __restrict__ Yrm,
                                             ushort* __restrict__ Yt,
                                             int Rr, int Cc) {
  __shared__ ushort tT[64][66];
  const int tid = threadIdx.x;
  const int r0 = blockIdx.x * 64, c0 = blockIdx.y * 64;
#pragma unroll
  for (int i = 0; i < 4; ++i) {
    const int idx = i * 256 + tid;
    const int r = idx >> 4, c4 = (idx & 15) * 4;
    float4 v = *(const float4*)(X + (size_t)(r0 + r) * Cc + c0 + c4);
    ushort u0 = f2bf(v.x), u1 = f2bf(v.y), u2 = f2bf(v.z), u3 = f2bf(v.w);
    if (ROWM) {
      ushort4 o = make_ushort4(u0, u1, u2, u3);
      *(ushort4*)(Yrm + (size_t)(r0 + r) * Cc + c0 + c4) = o;
    }
    if (TRANSP) {
      tT[c4 + 0][r] = u0; tT[c4 + 1][r] = u1;
      tT[c4 + 2][r] = u2; tT[c4 + 3][r] = u3;
    }
  }
  if (TRANSP) {
    __syncthreads();
#pragma unroll
    for (int i = 0; i < 4; ++i) {
      const int idx = i * 256 + tid;
      const int c = idx >> 4, r4 = (idx & 15) * 4;
      ushort4 o = make_ushort4(tT[c][r4], tT[c][r4 + 1], tT[c][r4 + 2], tT[c][r4 + 3]);
      *(ushort4*)(Yt + (size_t)(c0 + c) * Rr + r0 + r4) = o;
    }
  }
}

// ---------------------------------------------------------------------------
// Column softmax stats over bf16 mat. Block: 256 rows x all 512 cols.
// ---------------------------------------------------------------------------
__global__ __launch_bounds__(256) void k_colpart(const ushort* __restrict__ mat,
                                                 float* __restrict__ pm,
                                                 float* __restrict__ pz) {
  const int c8 = (threadIdx.x & 63) * 8;
  const int rq = threadIdx.x >> 6;
  const int r0 = blockIdx.x * 256;
  float m[8], z[8];
#pragma unroll
  for (int j = 0; j < 8; ++j) { m[j] = -INFINITY; z[j] = 0.f; }
  for (int r = r0 + rq; r < r0 + 256; r += 4) {
    s16x8 v = *(const s16x8*)(mat + (size_t)r * NP + c8);
#pragma unroll
    for (int j = 0; j < 8; ++j) {
      float f = bf2f((ushort)v[j]);
      float mm = fmaxf(m[j], f);
      z[j] = z[j] * __expf(m[j] - mm) + __expf(f - mm);
      m[j] = mm;
    }
  }
  __shared__ float sm[4][NP], sz[4][NP];
#pragma unroll
  for (int j = 0; j < 8; ++j) { sm[rq][c8 + j] = m[j]; sz[rq][c8 + j] = z[j]; }
  __syncthreads();
  if (rq == 0) {
#pragma unroll
    for (int j = 0; j < 8; ++j) {
      float mj = m[j], zj = z[j];
      for (int q = 1; q < 4; ++q) {
        float m2 = sm[q][c8 + j], z2 = sz[q][c8 + j];
        float mm = fmaxf(mj, m2);
        zj = zj * __expf(mj - mm) + z2 * __expf(m2 - mm);
        mj = mm;
      }
      pm[(size_t)blockIdx.x * NP + c8 + j] = mj;
      pz[(size_t)blockIdx.x * NP + c8 + j] = zj;
    }
  }
}

__global__ void k_colfinal(const float* __restrict__ pm, const float* __restrict__ pz,
                           float* __restrict__ colM, float* __restrict__ colIZ) {
  const int c = threadIdx.x;  // <<<1, NP>>>
  float m = -INFINITY, z = 0.f;
  for (int q = 0; q < BT / 256; ++q) {
    float m2 = pm[(size_t)q * NP + c], z2 = pz[(size_t)q * NP + c];
    float mm = fmaxf(m, m2);
    z = z * __expf(m - mm) + z2 * __expf(m2 - mm);
    m = mm;
  }
  colM[c] = m;
  colIZ[c] = 1.f / z;
}

// ---------------------------------------------------------------------------
// Row softmax stats over bf16 mat: one wave per token.
// ---------------------------------------------------------------------------
__global__ __launch_bounds__(256) void k_rowstats(const ushort* __restrict__ mat,
                                                  float* __restrict__ rowM,
                                                  float* __restrict__ rowIZ) {
  const int w = threadIdx.x >> 6;
  const int lane = threadIdx.x & 63;
  const int t = blockIdx.x * 4 + w;
  s16x8 v = *(const s16x8*)(mat + (size_t)t * NP + lane * 8);
  float f[8];
#pragma unroll
  for (int j = 0; j < 8; ++j) f[j] = bf2f((ushort)v[j]);
  float m = f[0];
#pragma unroll
  for (int j = 1; j < 8; ++j) m = fmaxf(m, f[j]);
#pragma unroll
  for (int o = 32; o; o >>= 1) m = fmaxf(m, __shfl_xor(m, o));
  float s = 0.f;
#pragma unroll
  for (int j = 0; j < 8; ++j) s += __expf(f[j] - m);
#pragma unroll
  for (int o = 32; o; o >>= 1) s += __shfl_xor(s, o);
  if (lane == 0) {
    rowM[t] = m;
    rowIZ[t] = 1.f / s;
  }
}

// ---------------------------------------------------------------------------
// Probabilities in bf16 from bf16 mat: Pc[t][s] and Pt[s][t]. 64x64 tiles.
// ---------------------------------------------------------------------------
__global__ __launch_bounds__(256) void k_probs(const ushort* __restrict__ mat,
                                               const float* __restrict__ colM,
                                               const float* __restrict__ colIZ,
                                               const float* __restrict__ rowM,
                                               const float* __restrict__ rowIZ,
                                               ushort* __restrict__ Pc,
                                               ushort* __restrict__ Pt) {
  __shared__ ushort tT[64][66];
  __shared__ float cm[64], cz[64], rm[64], rz[64];
  const int tid = threadIdx.x;
  const int t0 = blockIdx.x * 64, s0 = blockIdx.y * 64;
  if (tid < 64) {
    cm[tid] = colM[s0 + tid]; cz[tid] = colIZ[s0 + tid];
    rm[tid] = rowM[t0 + tid]; rz[tid] = rowIZ[t0 + tid];
  }
  __syncthreads();
#pragma unroll
  for (int i = 0; i < 2; ++i) {
    const int idx = i * 256 + tid;
    const int r = idx >> 3, c8 = (idx & 7) * 8;
    s16x8 v = *(const s16x8*)(mat + (size_t)(t0 + r) * NP + s0 + c8);
    const float mr = rm[r], zr = rz[r];
    s16x8 oc;
#pragma unroll
    for (int j = 0; j < 8; ++j) {
      float f = bf2f((ushort)v[j]);
      oc[j] = (short)f2bf(__expf(f - mr) * zr);
      tT[c8 + j][r] = f2bf(__expf(f - cm[c8 + j]) * cz[c8 + j]);
    }
    *(s16x8*)(Pc + (size_t)(t0 + r) * NP + s0 + c8) = oc;
  }
  __syncthreads();
#pragma unroll
  for (int i = 0; i < 2; ++i) {
    const int idx = i * 256 + tid;
    const int c = idx >> 3, r8 = (idx & 7) * 8;
    s16x8 o;
#pragma unroll
    for (int j = 0; j < 8; ++j) o[j] = (short)tT[c][r8 + j];
    *(s16x8*)(Pt + (size_t)(s0 + c) * BT + t0 + r8) = o;
  }
}

// ---------------------------------------------------------------------------
// Expert MLP layer (fp32, weight-streaming, memory-bound)
// ---------------------------------------------------------------------------
template <int K, int N, bool RELU>
__global__ __launch_bounds__(256) void k_mlp(const float* __restrict__ X,
                                             const float* __restrict__ W,
                                             const float* __restrict__ bias,
                                             float* __restrict__ Y) {
  __shared__ float xs[NS * K];
  const int tid = threadIdx.x;
  const int e = blockIdx.x;
  const float4* src = (const float4*)(X + (size_t)e * NS * K);
  float4* dst = (float4*)xs;
  constexpr int NV = (NS * K) / (4 * 256);
#pragma unroll
  for (int i = 0; i < NV; ++i) dst[tid + i * 256] = src[tid + i * 256];
  __syncthreads();
  const int j = blockIdx.y * 64 + (tid & 63);
  const int pr = tid >> 6;
  const float* w = W + (size_t)e * K * N + j;
  const float* x0 = xs + pr * K;
  const float* x1 = xs + (pr + 4) * K;
  float a0 = 0.f, a1 = 0.f;
#pragma unroll 8
  for (int k = 0; k < K; ++k) {
    float wv = w[(size_t)k * N];
    a0 += x0[k] * wv;
    a1 += x1[k] * wv;
  }
  const float bb = bias[(size_t)e * N + j];
  a0 += bb;
  a1 += bb;
  if (RELU) {
    a0 = fmaxf(a0, 0.f);
    a1 = fmaxf(a1, 0.f);
  }
  Y[((size_t)e * NS + pr) * N + j] = a0;
  Y[((size_t)e * NS + pr + 4) * N + j] = a1;
}

}  // namespace

extern "C" void kernel_launch(void* const* d_in, const int* in_sizes, int n_in,
                              void* d_out, int out_size, void* d_ws, size_t ws_size,
                              hipStream_t stream) {
  const float* tokens = (const float*)d_in[0];  // [BT, DIM]
  const float* em     = (const float*)d_in[1];  // [DIM, NP]
  const float* W1     = (const float*)d_in[2];
  const float* b1     = (const float*)d_in[3];
  const float* W2     = (const float*)d_in[4];
  const float* b2     = (const float*)d_in[5];
  const float* W3     = (const float*)d_in[6];
  const float* b3     = (const float*)d_in[7];
  float* out = (float*)d_out;

  char* w = (char*)d_ws;
  ushort* matb      = (ushort*)w; w += (size_t)BT * NP * 2;    // 32MB bf16 logits
  ushort* tokens_bf = (ushort*)w; w += (size_t)BT * DIM * 2;   // 64MB
  ushort* tokT      = (ushort*)w; w += (size_t)DIM * BT * 2;   // 64MB
  ushort* Pt        = (ushort*)w; w += (size_t)NP * BT * 2;    // 33.5MB
  ushort* Pc        = (ushort*)w; w += (size_t)BT * NP * 2;    // 33.5MB
  ushort* emT       = (ushort*)w; w += (size_t)NP * DIM * 2;
  ushort* yhatT     = (ushort*)w; w += (size_t)DIM * NP * 2;
  float*  pm        = (float*)w;  w += (size_t)(BT / 256) * NP * 4;
  float*  pz        = (float*)w;  w += (size_t)(BT / 256) * NP * 4;
  float*  colM      = (float*)w;  w += NP * 4;
  float*  colIZ     = (float*)w;  w += NP * 4;
  float*  rowM      = (float*)w;  w += BT * 4;
  float*  rowIZ     = (float*)w;  w += BT * 4;
  float*  xhat      = (float*)w;  w += (size_t)NP * DIM * 4;
  float*  h1        = (float*)w;  w += (size_t)NP * HID * 4;
  float*  h2        = (float*)w;  w += (size_t)NP * HID * 4;
  float*  yhat      = (float*)w;  w += (size_t)NP * DIM * 4;
  (void)ws_size; (void)in_sizes; (void)n_in; (void)out_size;

  // prep: one pass over fp32 tokens -> rowmajor bf16 + transposed bf16
  k_cvt<true, true><<<dim3(BT / 64, DIM / 64), 256, 0, stream>>>(tokens, tokens_bf, tokT, BT, DIM);
  k_cvt<false, true><<<dim3(DIM / 64, NP / 64), 256, 0, stream>>>(em, nullptr, emT, DIM, NP);
  // 1. routing logits (bf16 out), T1-swizzled
  k_gemm<false, true><<<dim3(NP / 128, BT / 128, 1), 256, 0, stream>>>(tokens_bf, emT, matb, DIM, NP, DIM);
  // 2. softmax stats
  k_colpart<<<BT / 256, 256, 0, stream>>>(matb, pm, pz);
  k_colfinal<<<1, NP, 0, stream>>>(pm, pz, colM, colIZ);
  k_rowstats<<<BT / 4, 256, 0, stream>>>(matb, rowM, rowIZ);
  // 3. probabilities in bf16 (Pc rowmajor, Pt transposed)
  k_probs<<<dim3(BT / 64, NP / 64), 256, 0, stream>>>(matb, colM, colIZ, rowM, rowIZ, Pc, Pt);
  // 4. dispatch: xhat = Pt @ tokens  (split-K 16, fp32 atomics), T1-swizzled
  hipMemsetAsync(xhat, 0, (size_t)NP * DIM * 4, stream);
  k_gemm<true, false><<<dim3(DIM / 128, NP / 128, 16), 256, 0, stream>>>(Pt, tokT, xhat, BT, DIM, BT / 16);
  // 5. expert MLPs (fp32)
  k_mlp<DIM, HID, true><<<dim3(NE, HID / 64), 256, 0, stream>>>(xhat, W1, b1, h1);
  k_mlp<HID, HID, true><<<dim3(NE, HID / 64), 256, 0, stream>>>(h1, W2, b2, h2);
  k_mlp<HID, DIM, false><<<dim3(NE, DIM / 64), 256, 0, stream>>>(h2, W3, b3, yhat);
  k_cvt<false, true><<<dim3(NP / 64, DIM / 64), 256, 0, stream>>>(yhat, nullptr, yhatT, NP, DIM);
  // 6. combine: out = Pc @ yhat, T1-swizzled
  k_gemm<false, false><<<dim3(DIM / 128, BT / 128, 1), 256, 0, stream>>>(Pc, yhatT, out, NP, DIM, NP);
}

// Round 5
// 438.199 us; speedup vs baseline: 3.5367x; 1.0315x over previous
//
#include <hip/hip_runtime.h>
#include <math.h>

namespace {

constexpr int BT  = 8 * 4096;   // 32768 tokens
constexpr int DIM = 1024;       // model dim
constexpr int NE  = 64;         // experts
constexpr int NS  = 8;          // slots per expert
constexpr int NP  = NE * NS;    // 512 total slots
constexpr int HID = 256;

typedef float f32x4 __attribute__((ext_vector_type(4)));
typedef __bf16 bf16x8 __attribute__((ext_vector_type(8)));
typedef short s16x8 __attribute__((ext_vector_type(8)));

__device__ __forceinline__ ushort f2bf(float x) {
  union { float f; unsigned u; } a; a.f = x;
  unsigned r = a.u + 0x7FFFu + ((a.u >> 16) & 1u);  // RNE
  return (ushort)(r >> 16);
}
__device__ __forceinline__ float bf2f(ushort u) {
  union { unsigned u; float f; } a; a.u = (unsigned)u << 16;
  return a.f;
}

__device__ __forceinline__ void gload16(const void* g, void* l) {
  __builtin_amdgcn_global_load_lds(
      (const __attribute__((address_space(1))) void*)g,
      (__attribute__((address_space(3))) void*)l, 16, 0, 0);
}

// ---------------------------------------------------------------------------
// bf16 MFMA GEMM: C[M][N] = A[M][K](bf16 rm) @ Bt[N][K](bf16)^T
// 128x128 tile, BK=32, 4 waves 2x2. T1 XCD-chunked swizzle (round 3).
// T3-min 2-phase double-buffer: STAGE(t+1) issued BEFORE compute(t); one
// __syncthreads() (vmcnt(0)+barrier) per K-step, so HBM latency of tile t+1
// hides under ds_read+MFMA of tile t.
// ---------------------------------------------------------------------------
template <bool ATOMIC, bool OBF>
__global__ __launch_bounds__(256) void k_gemm(const ushort* __restrict__ A,
                                              const ushort* __restrict__ Bt,
                                              void* __restrict__ Cv,
                                              int K, int N, int kchunk) {
  __shared__ __align__(16) ushort As[2][128 * 32];
  __shared__ __align__(16) ushort Bs[2][128 * 32];
  const int tid = threadIdx.x;
  const int wid = tid >> 6;
  const int lane = tid & 63;

  // T1 XCD-chunked swizzle (bijective: nwg % 8 == 0)
  const int gx = gridDim.x, gy = gridDim.y;
  int wg = (blockIdx.z * gy + blockIdx.y) * gx + blockIdx.x;
  const int nwg = gx * gy * gridDim.z;
  wg = (wg & 7) * (nwg >> 3) + (wg >> 3);
  const int bx = wg % gx;
  const int rest = wg / gx;
  const int by = rest % gy;
  const int bz = rest / gy;

  const int n0 = bx * 128;
  const int m0 = by * 128;
  const int kb = bz * kchunk;

  const int srow = tid >> 2;
  const int skoff = (tid & 3) * 8;

  const int wr = (wid >> 1) * 64;
  const int wc = (wid & 1) * 64;
  const int fr = lane & 15;
  const int fq = lane >> 4;

  f32x4 acc[4][4];
#pragma unroll
  for (int i = 0; i < 4; ++i)
#pragma unroll
    for (int j = 0; j < 4; ++j) acc[i][j] = (f32x4){0.f, 0.f, 0.f, 0.f};

  const ushort* Arow0 = A + (size_t)(m0 + srow) * K + skoff;
  const ushort* Arow1 = A + (size_t)(m0 + 64 + srow) * K + skoff;
  const ushort* Brow0 = Bt + (size_t)(n0 + srow) * K + skoff;
  const ushort* Brow1 = Bt + (size_t)(n0 + 64 + srow) * K + skoff;

  const int woff = wid * 512;  // wave's linear staging quarter (ushorts)

#define STAGE(b, kk)                              \
  do {                                            \
    ushort* as_ = &As[b][woff];                   \
    ushort* bs_ = &Bs[b][woff];                   \
    gload16(Arow0 + (kk), as_);                   \
    gload16(Arow1 + (kk), as_ + 2048);            \
    gload16(Brow0 + (kk), bs_);                   \
    gload16(Brow1 + (kk), bs_ + 2048);            \
  } while (0)

  const int nt = kchunk / 32;
  STAGE(0, kb);
  __syncthreads();  // drain prologue loads
  int cur = 0;
  for (int t = 0; t < nt; ++t) {
    if (t + 1 < nt) STAGE(cur ^ 1, kb + (t + 1) * 32);
    const ushort* Ab = &As[cur][0];
    const ushort* Bb = &Bs[cur][0];
    bf16x8 af[4], bfr[4];
#pragma unroll
    for (int m = 0; m < 4; ++m)
      af[m] = __builtin_bit_cast(
          bf16x8, *(const s16x8*)(Ab + (size_t)(wr + m * 16 + fr) * 32 + fq * 8));
#pragma unroll
    for (int n = 0; n < 4; ++n)
      bfr[n] = __builtin_bit_cast(
          bf16x8, *(const s16x8*)(Bb + (size_t)(wc + n * 16 + fr) * 32 + fq * 8));
#pragma unroll
    for (int m = 0; m < 4; ++m)
#pragma unroll
      for (int n = 0; n < 4; ++n)
        acc[m][n] = __builtin_amdgcn_mfma_f32_16x16x32_bf16(af[m], bfr[n], acc[m][n], 0, 0, 0);
    __syncthreads();  // vmcnt(0): next tile landed; all waves done reading cur
    cur ^= 1;
  }
#undef STAGE

  // C/D layout: col = lane&15, row = (lane>>4)*4 + reg   [m89-verified]
  if (OBF) {
    ushort* Cb = (ushort*)Cv + (size_t)(m0 + wr + fq * 4) * N + n0 + wc + fr;
#pragma unroll
    for (int m = 0; m < 4; ++m)
#pragma unroll
      for (int n = 0; n < 4; ++n)
#pragma unroll
        for (int r = 0; r < 4; ++r)
          Cb[(size_t)(m * 16 + r) * N + n * 16] = f2bf(acc[m][n][r]);
  } else {
    float* Cb = (float*)Cv + (size_t)(m0 + wr + fq * 4) * N + n0 + wc + fr;
#pragma unroll
    for (int m = 0; m < 4; ++m)
#pragma unroll
      for (int n = 0; n < 4; ++n)
#pragma unroll
        for (int r = 0; r < 4; ++r) {
          float* p = Cb + (size_t)(m * 16 + r) * N + n * 16;
          if (ATOMIC) atomicAdd(p, acc[m][n][r]);
          else *p = acc[m][n][r];
        }
  }
}

// ---------------------------------------------------------------------------
// fp32 [R][C] -> bf16 rowmajor and/or bf16 transposed, 64x64 tiles
// ---------------------------------------------------------------------------
template <bool ROWM, bool TRANSP>
__global__ __launch_bounds__(256) void k_cvt(const float* __restrict__ X,
                                             ushort* __restrict__ Yrm,
                                             ushort* __restrict__ Yt,
                                             int Rr, int Cc) {
  __shared__ ushort tT[64][66];
  const int tid = threadIdx.x;
  const int r0 = blockIdx.x * 64, c0 = blockIdx.y * 64;
#pragma unroll
  for (int i = 0; i < 4; ++i) {
    const int idx = i * 256 + tid;
    const int r = idx >> 4, c4 = (idx & 15) * 4;
    float4 v = *(const float4*)(X + (size_t)(r0 + r) * Cc + c0 + c4);
    ushort u0 = f2bf(v.x), u1 = f2bf(v.y), u2 = f2bf(v.z), u3 = f2bf(v.w);
    if (ROWM) {
      ushort4 o = make_ushort4(u0, u1, u2, u3);
      *(ushort4*)(Yrm + (size_t)(r0 + r) * Cc + c0 + c4) = o;
    }
    if (TRANSP) {
      tT[c4 + 0][r] = u0; tT[c4 + 1][r] = u1;
      tT[c4 + 2][r] = u2; tT[c4 + 3][r] = u3;
    }
  }
  if (TRANSP) {
    __syncthreads();
#pragma unroll
    for (int i = 0; i < 4; ++i) {
      const int idx = i * 256 + tid;
      const int c = idx >> 4, r4 = (idx & 15) * 4;
      ushort4 o = make_ushort4(tT[c][r4], tT[c][r4 + 1], tT[c][r4 + 2], tT[c][r4 + 3]);
      *(ushort4*)(Yt + (size_t)(c0 + c) * Rr + r0 + r4) = o;
    }
  }
}

// ---------------------------------------------------------------------------
// Column softmax stats over bf16 mat. Block: 256 rows x all 512 cols.
// ---------------------------------------------------------------------------
__global__ __launch_bounds__(256) void k_colpart(const ushort* __restrict__ mat,
                                                 float* __restrict__ pm,
                                                 float* __restrict__ pz) {
  const int c8 = (threadIdx.x & 63) * 8;
  const int rq = threadIdx.x >> 6;
  const int r0 = blockIdx.x * 256;
  float m[8], z[8];
#pragma unroll
  for (int j = 0; j < 8; ++j) { m[j] = -INFINITY; z[j] = 0.f; }
  for (int r = r0 + rq; r < r0 + 256; r += 4) {
    s16x8 v = *(const s16x8*)(mat + (size_t)r * NP + c8);
#pragma unroll
    for (int j = 0; j < 8; ++j) {
      float f = bf2f((ushort)v[j]);
      float mm = fmaxf(m[j], f);
      z[j] = z[j] * __expf(m[j] - mm) + __expf(f - mm);
      m[j] = mm;
    }
  }
  __shared__ float sm[4][NP], sz[4][NP];
#pragma unroll
  for (int j = 0; j < 8; ++j) { sm[rq][c8 + j] = m[j]; sz[rq][c8 + j] = z[j]; }
  __syncthreads();
  if (rq == 0) {
#pragma unroll
    for (int j = 0; j < 8; ++j) {
      float mj = m[j], zj = z[j];
      for (int q = 1; q < 4; ++q) {
        float m2 = sm[q][c8 + j], z2 = sz[q][c8 + j];
        float mm = fmaxf(mj, m2);
        zj = zj * __expf(mj - mm) + z2 * __expf(m2 - mm);
        mj = mm;
      }
      pm[(size_t)blockIdx.x * NP + c8 + j] = mj;
      pz[(size_t)blockIdx.x * NP + c8 + j] = zj;
    }
  }
}

__global__ void k_colfinal(const float* __restrict__ pm, const float* __restrict__ pz,
                           float* __restrict__ colM, float* __restrict__ colIZ) {
  const int c = threadIdx.x;  // <<<1, NP>>>
  float m = -INFINITY, z = 0.f;
  for (int q = 0; q < BT / 256; ++q) {
    float m2 = pm[(size_t)q * NP + c], z2 = pz[(size_t)q * NP + c];
    float mm = fmaxf(m, m2);
    z = z * __expf(m - mm) + z2 * __expf(m2 - mm);
    m = mm;
  }
  colM[c] = m;
  colIZ[c] = 1.f / z;
}

// ---------------------------------------------------------------------------
// Row softmax stats over bf16 mat: one wave per token.
// ---------------------------------------------------------------------------
__global__ __launch_bounds__(256) void k_rowstats(const ushort* __restrict__ mat,
                                                  float* __restrict__ rowM,
                                                  float* __restrict__ rowIZ) {
  const int w = threadIdx.x >> 6;
  const int lane = threadIdx.x & 63;
  const int t = blockIdx.x * 4 + w;
  s16x8 v = *(const s16x8*)(mat + (size_t)t * NP + lane * 8);
  float f[8];
#pragma unroll
  for (int j = 0; j < 8; ++j) f[j] = bf2f((ushort)v[j]);
  float m = f[0];
#pragma unroll
  for (int j = 1; j < 8; ++j) m = fmaxf(m, f[j]);
#pragma unroll
  for (int o = 32; o; o >>= 1) m = fmaxf(m, __shfl_xor(m, o));
  float s = 0.f;
#pragma unroll
  for (int j = 0; j < 8; ++j) s += __expf(f[j] - m);
#pragma unroll
  for (int o = 32; o; o >>= 1) s += __shfl_xor(s, o);
  if (lane == 0) {
    rowM[t] = m;
    rowIZ[t] = 1.f / s;
  }
}

// ---------------------------------------------------------------------------
// Probabilities in bf16 from bf16 mat: Pc[t][s] and Pt[s][t]. 64x64 tiles.
// ---------------------------------------------------------------------------
__global__ __launch_bounds__(256) void k_probs(const ushort* __restrict__ mat,
                                               const float* __restrict__ colM,
                                               const float* __restrict__ colIZ,
                                               const float* __restrict__ rowM,
                                               const float* __restrict__ rowIZ,
                                               ushort* __restrict__ Pc,
                                               ushort* __restrict__ Pt) {
  __shared__ ushort tT[64][66];
  __shared__ float cm[64], cz[64], rm[64], rz[64];
  const int tid = threadIdx.x;
  const int t0 = blockIdx.x * 64, s0 = blockIdx.y * 64;
  if (tid < 64) {
    cm[tid] = colM[s0 + tid]; cz[tid] = colIZ[s0 + tid];
    rm[tid] = rowM[t0 + tid]; rz[tid] = rowIZ[t0 + tid];
  }
  __syncthreads();
#pragma unroll
  for (int i = 0; i < 2; ++i) {
    const int idx = i * 256 + tid;
    const int r = idx >> 3, c8 = (idx & 7) * 8;
    s16x8 v = *(const s16x8*)(mat + (size_t)(t0 + r) * NP + s0 + c8);
    const float mr = rm[r], zr = rz[r];
    s16x8 oc;
#pragma unroll
    for (int j = 0; j < 8; ++j) {
      float f = bf2f((ushort)v[j]);
      oc[j] = (short)f2bf(__expf(f - mr) * zr);
      tT[c8 + j][r] = f2bf(__expf(f - cm[c8 + j]) * cz[c8 + j]);
    }
    *(s16x8*)(Pc + (size_t)(t0 + r) * NP + s0 + c8) = oc;
  }
  __syncthreads();
#pragma unroll
  for (int i = 0; i < 2; ++i) {
    const int idx = i * 256 + tid;
    const int c = idx >> 3, r8 = (idx & 7) * 8;
    s16x8 o;
#pragma unroll
    for (int j = 0; j < 8; ++j) o[j] = (short)tT[c][r8 + j];
    *(s16x8*)(Pt + (size_t)(s0 + c) * BT + t0 + r8) = o;
  }
}

// ---------------------------------------------------------------------------
// Expert MLP layer (fp32, weight-streaming, memory-bound)
// ---------------------------------------------------------------------------
template <int K, int N, bool RELU>
__global__ __launch_bounds__(256) void k_mlp(const float* __restrict__ X,
                                             const float* __restrict__ W,
                                             const float* __restrict__ bias,
                                             float* __restrict__ Y) {
  __shared__ float xs[NS * K];
  const int tid = threadIdx.x;
  const int e = blockIdx.x;
  const float4* src = (const float4*)(X + (size_t)e * NS * K);
  float4* dst = (float4*)xs;
  constexpr int NV = (NS * K) / (4 * 256);
#pragma unroll
  for (int i = 0; i < NV; ++i) dst[tid + i * 256] = src[tid + i * 256];
  __syncthreads();
  const int j = blockIdx.y * 64 + (tid & 63);
  const int pr = tid >> 6;
  const float* w = W + (size_t)e * K * N + j;
  const float* x0 = xs + pr * K;
  const float* x1 = xs + (pr + 4) * K;
  float a0 = 0.f, a1 = 0.f;
#pragma unroll 8
  for (int k = 0; k < K; ++k) {
    float wv = w[(size_t)k * N];
    a0 += x0[k] * wv;
    a1 += x1[k] * wv;
  }
  const float bb = bias[(size_t)e * N + j];
  a0 += bb;
  a1 += bb;
  if (RELU) {
    a0 = fmaxf(a0, 0.f);
    a1 = fmaxf(a1, 0.f);
  }
  Y[((size_t)e * NS + pr) * N + j] = a0;
  Y[((size_t)e * NS + pr + 4) * N + j] = a1;
}

}  // namespace

extern "C" void kernel_launch(void* const* d_in, const int* in_sizes, int n_in,
                              void* d_out, int out_size, void* d_ws, size_t ws_size,
                              hipStream_t stream) {
  const float* tokens = (const float*)d_in[0];  // [BT, DIM]
  const float* em     = (const float*)d_in[1];  // [DIM, NP]
  const float* W1     = (const float*)d_in[2];
  const float* b1     = (const float*)d_in[3];
  const float* W2     = (const float*)d_in[4];
  const float* b2     = (const float*)d_in[5];
  const float* W3     = (const float*)d_in[6];
  const float* b3     = (const float*)d_in[7];
  float* out = (float*)d_out;

  char* w = (char*)d_ws;
  ushort* matb      = (ushort*)w; w += (size_t)BT * NP * 2;    // 32MB bf16 logits
  ushort* tokens_bf = (ushort*)w; w += (size_t)BT * DIM * 2;   // 64MB
  ushort* tokT      = (ushort*)w; w += (size_t)DIM * BT * 2;   // 64MB
  ushort* Pt        = (ushort*)w; w += (size_t)NP * BT * 2;    // 33.5MB
  ushort* Pc        = (ushort*)w; w += (size_t)BT * NP * 2;    // 33.5MB
  ushort* emT       = (ushort*)w; w += (size_t)NP * DIM * 2;
  ushort* yhatT     = (ushort*)w; w += (size_t)DIM * NP * 2;
  float*  pm        = (float*)w;  w += (size_t)(BT / 256) * NP * 4;
  float*  pz        = (float*)w;  w += (size_t)(BT / 256) * NP * 4;
  float*  colM      = (float*)w;  w += NP * 4;
  float*  colIZ     = (float*)w;  w += NP * 4;
  float*  rowM      = (float*)w;  w += BT * 4;
  float*  rowIZ     = (float*)w;  w += BT * 4;
  float*  xhat      = (float*)w;  w += (size_t)NP * DIM * 4;
  float*  h1        = (float*)w;  w += (size_t)NP * HID * 4;
  float*  h2        = (float*)w;  w += (size_t)NP * HID * 4;
  float*  yhat      = (float*)w;  w += (size_t)NP * DIM * 4;
  (void)ws_size; (void)in_sizes; (void)n_in; (void)out_size;

  // prep: one pass over fp32 tokens -> rowmajor bf16 + transposed bf16
  k_cvt<true, true><<<dim3(BT / 64, DIM / 64), 256, 0, stream>>>(tokens, tokens_bf, tokT, BT, DIM);
  k_cvt<false, true><<<dim3(DIM / 64, NP / 64), 256, 0, stream>>>(em, nullptr, emT, DIM, NP);
  // 1. routing logits (bf16 out), T1-swizzled, 2-phase pipelined
  k_gemm<false, true><<<dim3(NP / 128, BT / 128, 1), 256, 0, stream>>>(tokens_bf, emT, matb, DIM, NP, DIM);
  // 2. softmax stats
  k_colpart<<<BT / 256, 256, 0, stream>>>(matb, pm, pz);
  k_colfinal<<<1, NP, 0, stream>>>(pm, pz, colM, colIZ);
  k_rowstats<<<BT / 4, 256, 0, stream>>>(matb, rowM, rowIZ);
  // 3. probabilities in bf16 (Pc rowmajor, Pt transposed)
  k_probs<<<dim3(BT / 64, NP / 64), 256, 0, stream>>>(matb, colM, colIZ, rowM, rowIZ, Pc, Pt);
  // 4. dispatch: xhat = Pt @ tokens  (split-K 16, fp32 atomics), T1-swizzled
  hipMemsetAsync(xhat, 0, (size_t)NP * DIM * 4, stream);
  k_gemm<true, false><<<dim3(DIM / 128, NP / 128, 16), 256, 0, stream>>>(Pt, tokT, xhat, BT, DIM, BT / 16);
  // 5. expert MLPs (fp32)
  k_mlp<DIM, HID, true><<<dim3(NE, HID / 64), 256, 0, stream>>>(xhat, W1, b1, h1);
  k_mlp<HID, HID, true><<<dim3(NE, HID / 64), 256, 0, stream>>>(h1, W2, b2, h2);
  k_mlp<HID, DIM, false><<<dim3(NE, DIM / 64), 256, 0, stream>>>(h2, W3, b3, yhat);
  k_cvt<false, true><<<dim3(NP / 64, DIM / 64), 256, 0, stream>>>(yhat, nullptr, yhatT, NP, DIM);
  // 6. combine: out = Pc @ yhat, T1-swizzled, 2-phase pipelined
  k_gemm<false, false><<<dim3(DIM / 128, BT / 128, 1), 256, 0, stream>>>(Pc, yhatT, out, NP, DIM, NP);
}